// Round 3
// baseline (540.488 us; speedup 1.0000x reference)
//
#include <hip/hip_runtime.h>
#include <math.h>

// NetNew_17162689315115: 8-layer EQL-style net, B=524288 rows.
// Harness reference is numpy float64 ("ref=np", threshold = 2% of max|ref|).
// The map is chaotic (sin/cos of |z|~1e7), so fp32 anywhere in the chain
// injects 1e-7-rel errors that decorrelate the tail rows (round1: 2.58e6,
// round2: 9.3e7). Fix: full float64 chain, cast to f32 only at the store.
// One thread per row; h[80] doubles register-resident via full unrolling.

static constexpr double MAX_MLT   = 99999999.0;
static constexpr double MAX_DIV   = 9999.0;
static constexpr double MAX_EXP_C = 17.0;
static constexpr double MIN_DENOM = 0.0001;

static constexpr int IN0  = 8;   // vari_num + const_num
static constexpr int VDIM = 13;  // rows of each W
static constexpr int NOPS = 9;   // ops appended per layer
static constexpr int FDIM = 80;  // final h dim: 8 + 8*9

// _clip_mag forward, float64: scale = |mx/v|, o = where(|v|>=mx, v*scale, v).
// NaN passes through (compare false), matching jnp.where.
__device__ __forceinline__ double clip_ref(double v, double mx) {
    double scale = fabs(mx / v);
    double vs    = v * scale;
    return (fabs(v) >= mx) ? vs : v;
}

template<int IN_DIM, int BASE>
__device__ __forceinline__ void layer_step(const float* __restrict__ W,
                                           double (&h)[FDIM]) {
    double z[VDIM];
    #pragma unroll
    for (int j = 0; j < VDIM; ++j) {
        double acc = 0.0;
        #pragma unroll
        for (int k = 0; k < IN_DIM; ++k) {
            acc = fma((double)W[j * IN_DIM + k], h[BASE + k], acc);
        }
        z[j] = acc;
    }
    constexpr int BO = BASE - NOPS;
    // op order: + - * / sin cos exp log square, consuming z cols in order
    h[BO + 0] = z[0] + z[1];
    h[BO + 1] = z[2] - z[3];
    h[BO + 2] = clip_ref(z[4] * z[5], MAX_MLT);
    {
        double b     = z[7];
        double denom = (b == 0.0) ? (b + MIN_DENOM) : b;
        h[BO + 3]    = clip_ref(z[6] / denom, MAX_DIV);
    }
    h[BO + 4] = sin(z[8]);
    h[BO + 5] = cos(z[9]);
    {
        double a    = z[10];
        double safe = (a >= MAX_EXP_C) ? (a * (MAX_EXP_C / a)) : a;
        h[BO + 6]   = exp(safe);
    }
    h[BO + 7] = log(fabs(z[11]));
    h[BO + 8] = clip_ref(z[12] * z[12], MAX_MLT);
}

__global__ void __launch_bounds__(256)
net_kernel(const float* __restrict__ x,
           const float* __restrict__ W1, const float* __restrict__ W2,
           const float* __restrict__ W3, const float* __restrict__ W4,
           const float* __restrict__ W5, const float* __restrict__ W6,
           const float* __restrict__ W7, const float* __restrict__ W8,
           const float* __restrict__ Wf,
           float* __restrict__ out, int nrows) {
    int row = blockIdx.x * blockDim.x + threadIdx.x;
    if (row >= nrows) return;

    double h[FDIM];

    // x occupies the TAIL of the final feature vector (each layer prepends).
    const float4* x4 = reinterpret_cast<const float4*>(x);
    float4 xa = x4[row * 2 + 0];
    float4 xb = x4[row * 2 + 1];
    h[72] = (double)xa.x; h[73] = (double)xa.y; h[74] = (double)xa.z; h[75] = (double)xa.w;
    h[76] = (double)xb.x; h[77] = (double)xb.y; h[78] = (double)xb.z; h[79] = (double)xb.w;

    layer_step<IN0 + 0 * NOPS, 72>(W1, h);  // in_dim  8, write at 63
    layer_step<IN0 + 1 * NOPS, 63>(W2, h);  // in_dim 17, write at 54
    layer_step<IN0 + 2 * NOPS, 54>(W3, h);  // in_dim 26, write at 45
    layer_step<IN0 + 3 * NOPS, 45>(W4, h);  // in_dim 35, write at 36
    layer_step<IN0 + 4 * NOPS, 36>(W5, h);  // in_dim 44, write at 27
    layer_step<IN0 + 5 * NOPS, 27>(W6, h);  // in_dim 53, write at 18
    layer_step<IN0 + 6 * NOPS, 18>(W7, h);  // in_dim 62, write at  9
    layer_step<IN0 + 7 * NOPS,  9>(W8, h);  // in_dim 71, write at  0

    double acc = 0.0;
    #pragma unroll
    for (int k = 0; k < FDIM; ++k) {
        acc = fma((double)Wf[k], h[k], acc);
    }
    out[row] = (float)acc;
}

extern "C" void kernel_launch(void* const* d_in, const int* in_sizes, int n_in,
                              void* d_out, int out_size, void* d_ws, size_t ws_size,
                              hipStream_t stream) {
    const float* x  = (const float*)d_in[0];
    const float* W1 = (const float*)d_in[1];
    const float* W2 = (const float*)d_in[2];
    const float* W3 = (const float*)d_in[3];
    const float* W4 = (const float*)d_in[4];
    const float* W5 = (const float*)d_in[5];
    const float* W6 = (const float*)d_in[6];
    const float* W7 = (const float*)d_in[7];
    const float* W8 = (const float*)d_in[8];
    const float* Wf = (const float*)d_in[9];
    float* out = (float*)d_out;

    int nrows = in_sizes[0] / IN0;
    int block = 256;
    int grid  = (nrows + block - 1) / block;
    net_kernel<<<grid, block, 0, stream>>>(x, W1, W2, W3, W4, W5, W6, W7, W8,
                                           Wf, out, nrows);
}

// Round 4
// 463.814 us; speedup vs baseline: 1.1653x; 1.1653x over previous
//
#include <hip/hip_runtime.h>
#include <math.h>

// NetNew_17162689315115: 8-layer EQL-style net, B=524288 rows.
// Reference is numpy float64; the map is chaotic (sin/cos at |z|~1e7-1e9), so
// the ENTIRE chain runs in fp64 (round 3: passed, absmax 1.245e6 / thr 1.65e6).
// DO NOT reassociate the matmul or touch precision — bitwise-frozen numerics.
//
// Round 4 perf change (bitwise-neutral): weights are fp32 in memory, which put
// a v_cvt_f64_f32 on every one of the 4268 FMAs/row. A prep kernel widens all
// weights to fp64 into d_ws once per call; the main kernel then does
// s_load_dwordx2 (scalar pipe) -> v_fma_f64 with no per-FMA convert.

static constexpr double MAX_MLT   = 99999999.0;
static constexpr double MAX_DIV   = 9999.0;
static constexpr double MAX_EXP_C = 17.0;
static constexpr double MIN_DENOM = 0.0001;

static constexpr int IN0  = 8;   // vari_num + const_num
static constexpr int VDIM = 13;  // rows of each W
static constexpr int NOPS = 9;   // ops appended per layer
static constexpr int FDIM = 80;  // final h dim: 8 + 8*9

// layer weight element counts and fp64 workspace offsets
// in_dims: 8,17,26,35,44,53,62,71 ; W_i is 13 x in_dim ; Wf is 1 x 80
static constexpr int WSZ[9]  = {104, 221, 338, 455, 572, 689, 806, 923, 80};
static constexpr int WOFF[9] = {0, 104, 325, 663, 1118, 1690, 2379, 3185, 4108};
static constexpr int WTOT    = 4188;  // doubles

// ---- prep: widen fp32 weights -> fp64 workspace (exact, bitwise-neutral) ----
__global__ void widen_kernel(const float* __restrict__ s0, const float* __restrict__ s1,
                             const float* __restrict__ s2, const float* __restrict__ s3,
                             const float* __restrict__ s4, const float* __restrict__ s5,
                             const float* __restrict__ s6, const float* __restrict__ s7,
                             const float* __restrict__ s8, double* __restrict__ dst) {
    int seg = blockIdx.y;
    int i   = blockIdx.x * blockDim.x + threadIdx.x;
    const float* src;
    switch (seg) {
        case 0: src = s0; break; case 1: src = s1; break; case 2: src = s2; break;
        case 3: src = s3; break; case 4: src = s4; break; case 5: src = s5; break;
        case 6: src = s6; break; case 7: src = s7; break; default: src = s8; break;
    }
    if (i < WSZ[seg]) dst[WOFF[seg] + i] = (double)src[i];
}

// _clip_mag forward, float64: scale = |mx/v|, o = where(|v|>=mx, v*scale, v).
// NaN passes through (compare false), matching jnp.where.
__device__ __forceinline__ double clip_ref(double v, double mx) {
    double scale = fabs(mx / v);
    double vs    = v * scale;
    return (fabs(v) >= mx) ? vs : v;
}

template<int IN_DIM, int BASE>
__device__ __forceinline__ void layer_step(const double* __restrict__ W,
                                           double (&h)[FDIM]) {
    double z[VDIM];
    #pragma unroll
    for (int j = 0; j < VDIM; ++j) {
        double acc = 0.0;
        #pragma unroll
        for (int k = 0; k < IN_DIM; ++k) {
            acc = fma(W[j * IN_DIM + k], h[BASE + k], acc);  // frozen accum order
        }
        z[j] = acc;
    }
    constexpr int BO = BASE - NOPS;
    // op order: + - * / sin cos exp log square, consuming z cols in order
    h[BO + 0] = z[0] + z[1];
    h[BO + 1] = z[2] - z[3];
    h[BO + 2] = clip_ref(z[4] * z[5], MAX_MLT);
    {
        double b     = z[7];
        double denom = (b == 0.0) ? (b + MIN_DENOM) : b;
        h[BO + 3]    = clip_ref(z[6] / denom, MAX_DIV);
    }
    h[BO + 4] = sin(z[8]);
    h[BO + 5] = cos(z[9]);
    {
        double a    = z[10];
        double safe = (a >= MAX_EXP_C) ? (a * (MAX_EXP_C / a)) : a;
        h[BO + 6]   = exp(safe);
    }
    h[BO + 7] = log(fabs(z[11]));
    h[BO + 8] = clip_ref(z[12] * z[12], MAX_MLT);
}

__global__ void __launch_bounds__(256)
net_kernel(const float* __restrict__ x, const double* __restrict__ Wd,
           float* __restrict__ out, int nrows) {
    int row = blockIdx.x * blockDim.x + threadIdx.x;
    if (row >= nrows) return;

    double h[FDIM];

    // x occupies the TAIL of the final feature vector (each layer prepends).
    const float4* x4 = reinterpret_cast<const float4*>(x);
    float4 xa = x4[row * 2 + 0];
    float4 xb = x4[row * 2 + 1];
    h[72] = (double)xa.x; h[73] = (double)xa.y; h[74] = (double)xa.z; h[75] = (double)xa.w;
    h[76] = (double)xb.x; h[77] = (double)xb.y; h[78] = (double)xb.z; h[79] = (double)xb.w;

    layer_step<IN0 + 0 * NOPS, 72>(Wd + WOFF[0], h);  // in_dim  8, write at 63
    layer_step<IN0 + 1 * NOPS, 63>(Wd + WOFF[1], h);  // in_dim 17, write at 54
    layer_step<IN0 + 2 * NOPS, 54>(Wd + WOFF[2], h);  // in_dim 26, write at 45
    layer_step<IN0 + 3 * NOPS, 45>(Wd + WOFF[3], h);  // in_dim 35, write at 36
    layer_step<IN0 + 4 * NOPS, 36>(Wd + WOFF[4], h);  // in_dim 44, write at 27
    layer_step<IN0 + 5 * NOPS, 27>(Wd + WOFF[5], h);  // in_dim 53, write at 18
    layer_step<IN0 + 6 * NOPS, 18>(Wd + WOFF[6], h);  // in_dim 62, write at  9
    layer_step<IN0 + 7 * NOPS,  9>(Wd + WOFF[7], h);  // in_dim 71, write at  0

    const double* Wf = Wd + WOFF[8];
    double acc = 0.0;
    #pragma unroll
    for (int k = 0; k < FDIM; ++k) {
        acc = fma(Wf[k], h[k], acc);
    }
    out[row] = (float)acc;
}

extern "C" void kernel_launch(void* const* d_in, const int* in_sizes, int n_in,
                              void* d_out, int out_size, void* d_ws, size_t ws_size,
                              hipStream_t stream) {
    const float* x = (const float*)d_in[0];
    double* Wd     = (double*)d_ws;   // WTOT doubles = 33.5 KB
    float* out     = (float*)d_out;

    // widen weights (d_ws is re-poisoned before every call -> must rewrite)
    {
        dim3 grid((923 + 255) / 256, 9);
        widen_kernel<<<grid, 256, 0, stream>>>(
            (const float*)d_in[1], (const float*)d_in[2], (const float*)d_in[3],
            (const float*)d_in[4], (const float*)d_in[5], (const float*)d_in[6],
            (const float*)d_in[7], (const float*)d_in[8], (const float*)d_in[9],
            Wd);
    }

    int nrows = in_sizes[0] / IN0;
    int block = 256;
    int grid  = (nrows + block - 1) / block;
    net_kernel<<<grid, block, 0, stream>>>(x, Wd, out, nrows);
}